// Round 14
// baseline (53.552 us; speedup 1.0000x reference)
//
#include <hip/hip_runtime.h>
#include <math.h>

#define HH 256
#define WW 256
#define HWSZ (HH * WW)
#define KE 4096
#define NSLICE 16
#define NCHD 8                 // query chunks per (slice,dir) in edt_nn
#define GSENT 1024             // empty-column sentinel: 1024^2 > max real d2 (130050)

typedef unsigned long long u64;
typedef unsigned short u16;

// ---------------------------------------------------------------------------
// K1: binarize + bit-pack (r6-verbatim wide shape: full-chip BW for the one
// big read). One block per image row (2 x 16 x 256 = 8192). Lane thresholds
// one pixel; ballot packs 64 cols -> u64. bm layout: [tensor][slice][row][w4].
// ---------------------------------------------------------------------------
__global__ void __launch_bounds__(256) binarize_pack(
        const float* __restrict__ gth, const float* __restrict__ pred,
        u64* __restrict__ bm) {
    int b = blockIdx.x;                 // tensor*4096 + slice*256 + row
    int tensor = b >> 12;
    int sr = b & 4095;
    const float* img = tensor ? pred : gth;
    float v = img[sr * WW + threadIdx.x];
    u64 bal = __ballot(v > 0.5f);
    if ((threadIdx.x & 63) == 0) bm[(size_t)b * 4 + (threadIdx.x >> 6)] = bal;
}

// ---------------------------------------------------------------------------
// K2: bitwise edge detect + ordered compaction + truncated edge bitmap
// (r6-verbatim). 32 blocks (tensor,slice), thread = row.
//   vert  = rowAbove & row & rowBelow      (OOB row = all-ones)
//   erode = vert & shl1 & shr1             (OOB col carry-in = 1)
//   edge  = row & ~erode
// Row popcounts -> block scan -> ordered point writes (row-major ==
// jnp.nonzero). ebm keeps only bits of row-major rank < KE. cnt = FULL count.
// ---------------------------------------------------------------------------
__global__ void __launch_bounds__(256) edge_compact(
        const u64* __restrict__ bm,
        float2* __restrict__ gpts, float2* __restrict__ ppts,
        u64* __restrict__ ebm,
        int* __restrict__ gcnt, int* __restrict__ pcnt) {
    int b = blockIdx.x;                 // 0..31  (tensor*16 + slice)
    int tensor = b >> 4;
    int slice = b & 15;
    const u64* rm = bm + (size_t)(tensor * 4096 + slice * 256) * 4;
    float2* pts = (tensor ? ppts : gpts) + slice * KE;
    int* cnt = (tensor ? pcnt : gcnt) + slice;
    u64* eb = ebm + (size_t)b * 1024;   // 256 rows x 4 words

    int row = threadIdx.x;
    u64 vc[4], va[4], vb[4];
#pragma unroll
    for (int w = 0; w < 4; ++w) {
        vc[w] = rm[row * 4 + w];
        va[w] = (row > 0) ? rm[(row - 1) * 4 + w] : ~0ull;
        vb[w] = (row < HH - 1) ? rm[(row + 1) * 4 + w] : ~0ull;
    }
    u64 vert[4];
#pragma unroll
    for (int w = 0; w < 4; ++w) vert[w] = va[w] & vc[w] & vb[w];
    u64 e[4];
#pragma unroll
    for (int w = 0; w < 4; ++w) {
        u64 left  = (vert[w] << 1) | ((w > 0) ? (vert[w - 1] >> 63) : 1ull);
        u64 right = (vert[w] >> 1) | (((w < 3) ? (vert[w + 1] & 1ull) : 1ull) << 63);
        e[w] = vc[w] & ~(vert[w] & left & right);
    }
    int mycnt = __popcll(e[0]) + __popcll(e[1]) + __popcll(e[2]) + __popcll(e[3]);

    __shared__ int sc[256];
    sc[row] = mycnt;
    __syncthreads();
    for (int d = 1; d < 256; d <<= 1) {
        int v = (row >= d) ? sc[row - d] : 0;
        __syncthreads();
        sc[row] += v;
        __syncthreads();
    }
    int off = sc[row] - mycnt;          // exclusive prefix (row-major rank)

    // Truncated edge bitmap: keep only bits with rank < KE.
    int rem = KE - off;
    u64 t[4];
    if (rem >= mycnt) {
#pragma unroll
        for (int w = 0; w < 4; ++w) t[w] = e[w];
    } else if (rem <= 0) {
#pragma unroll
        for (int w = 0; w < 4; ++w) t[w] = 0ull;
    } else {
        int k = rem;
#pragma unroll
        for (int w = 0; w < 4; ++w) {
            int pc = __popcll(e[w]);
            if (k >= pc) { t[w] = e[w]; k -= pc; }
            else {
                u64 bits = e[w], keep = 0ull;
                for (int i = 0; i < k; ++i) {
                    u64 low = bits & (~bits + 1ull);
                    keep |= low;
                    bits ^= low;
                }
                t[w] = keep;
                k = 0;
            }
        }
    }
#pragma unroll
    for (int w = 0; w < 4; ++w) eb[row * 4 + w] = t[w];

    // Ordered point-list writes (queries; first KE in row-major order).
    int o = off;
#pragma unroll
    for (int w = 0; w < 4; ++w) {
        u64 bits = e[w];
        while (bits) {
            int l = __ffsll((long long)bits) - 1;
            bits &= bits - 1;
            if (o < KE) pts[o] = make_float2((float)row, (float)(w * 64 + l));
            ++o;
        }
    }
    if (row == HH - 1) *cnt = sc[HH - 1];
}

// ---------------------------------------------------------------------------
// G storage swizzle (r7-proven, absmax=0 there): u16 index of (r,c) with
// 16B-chunk XOR so query-phase reads (different r per lane, same chunk j)
// spread across bank groups.
// ---------------------------------------------------------------------------
__device__ __forceinline__ int gidx(int r, int c) {
    int cj = (c >> 3) ^ (r & 7);
    return r * WW + cj * 8 + (c & 7);
}

// ---------------------------------------------------------------------------
// K3: fused vertical-EDT + NN scan. Grid = 32 sd x 8 chunks = 256 blocks
// x 256 thr; dynamic LDS = 8 KB bitmap + 128 KB G (1 block/CU).
//  Phase A: stage target truncated edge bitmap -> LDS (coalesced).
//  Phase B: thread = column c: gather column bits into 4 u64 registers
//    (wave-uniform LDS reads -> broadcast), then down-scan + up-scan over
//    256 rows -> G[r][c] = min |r-r'| (u16, swizzled LDS stores; column-
//    exclusive, race-free). 8x redundant across chunk blocks -- cheap.
//  Phase C: 512 queries (2/thread): d2 = min_{c'} ((c-c')^2 + G[r][c']^2),
//    exact ints over 32 de-swizzled uint4 LDS reads; sqrt matches reference
//    bitwise. Fixed-order block reduce -> partial[b]. No atomics.
// ---------------------------------------------------------------------------
__global__ void __launch_bounds__(256) edt_nn(
        const float2* __restrict__ gpts, const float2* __restrict__ ppts,
        const int* __restrict__ gcnt, const int* __restrict__ pcnt,
        const u64* __restrict__ ebm, float* __restrict__ partial) {
    extern __shared__ char smem[];
    u64* ebl = (u64*)smem;              // [0, 8192)
    u16* G   = (u16*)(smem + 8192);     // [8192, 139264)
    __shared__ float red[4];

    int b = blockIdx.x;                 // sd*NCHD + chunk
    int chunk = b & (NCHD - 1);
    int sd = b >> 3;                    // slice*2 + dir
    int dir = sd & 1;
    int slice = sd >> 1;
    int tid = threadIdx.x;

    // ---- Phase A ----
    int tt = dir ? 0 : 1;               // target map tensor
    const u64* eb = ebm + (size_t)(tt * 16 + slice) * 1024;
    for (int i = tid; i < 1024; i += 256) ebl[i] = eb[i];
    __syncthreads();

    // ---- Phase B: per-column EDT ----
    int c = tid, cw = c >> 6, cb = c & 63;
    u64 w0 = 0, w1 = 0, w2 = 0, w3 = 0;
#pragma unroll 4
    for (int r = 0; r < 64; ++r) {
        w0 |= ((ebl[(r      ) * 4 + cw] >> cb) & 1ull) << r;
        w1 |= ((ebl[(r +  64) * 4 + cw] >> cb) & 1ull) << r;
        w2 |= ((ebl[(r + 128) * 4 + cw] >> cb) & 1ull) << r;
        w3 |= ((ebl[(r + 192) * 4 + cw] >> cb) & 1ull) << r;
    }
    int g = GSENT;
#define DPASS(wrd, base)                                                    \
    for (int i = 0; i < 64; ++i) {                                          \
        int bit = (int)((wrd >> i) & 1ull);                                 \
        g = bit ? 0 : min(g + 1, GSENT);                                    \
        G[gidx(base + i, c)] = (u16)g;                                      \
    }
    DPASS(w0, 0) DPASS(w1, 64) DPASS(w2, 128) DPASS(w3, 192)
#undef DPASS
    g = GSENT;
#define UPASS(wrd, base)                                                    \
    for (int i = 63; i >= 0; --i) {                                         \
        int bit = (int)((wrd >> i) & 1ull);                                 \
        g = bit ? 0 : min(g + 1, GSENT);                                    \
        int ix = gidx(base + i, c);                                         \
        G[ix] = (u16)min((int)G[ix], g);                                    \
    }
    UPASS(w3, 192) UPASS(w2, 128) UPASS(w1, 64) UPASS(w0, 0)
#undef UPASS
    __syncthreads();

    // ---- Phase C: queries ----
    int qfull = dir ? pcnt[slice] : gcnt[slice];
    int qc = min(qfull, KE);
    const float2* q = (dir ? ppts : gpts) + slice * KE;
    float val = 0.0f;
#pragma unroll
    for (int k = 0; k < 2; ++k) {
        int qi = chunk * 512 + k * 256 + tid;
        if (qi < qc) {
            float2 qp = q[qi];
            int r = (int)qp.x, cc = (int)qp.y;
            const uint4* grow = (const uint4*)(G + r * WW);
            int rsw = r & 7;
            int m = 0x7fffffff;
#pragma unroll
            for (int j = 0; j < 32; ++j) {
                uint4 v = grow[j ^ rsw];    // chunk j (cols 8j..8j+7)
                int bs = j * 8;
#define STEP(word, k0)                                                      \
                {                                                           \
                    int g0 = (int)((word) & 0xffffu);                       \
                    int g1 = (int)((word) >> 16);                           \
                    int d0 = cc - (bs + k0);                                \
                    int d1 = cc - (bs + k0 + 1);                            \
                    m = min(m, d0 * d0 + g0 * g0);                          \
                    m = min(m, d1 * d1 + g1 * g1);                          \
                }
                STEP(v.x, 0) STEP(v.y, 2) STEP(v.z, 4) STEP(v.w, 6)
#undef STEP
            }
            val += sqrtf((float)m);
        }
    }
    for (int s = 32; s > 0; s >>= 1) val += __shfl_xor(val, s, 64);
    if ((tid & 63) == 0) red[tid >> 6] = val;
    __syncthreads();
    if (tid == 0) partial[b] = red[0] + red[1] + red[2] + red[3];
}

// ---------------------------------------------------------------------------
// K4: fold 256 partials -> per-slice ahd -> loss -> nanmean. 1 block x 256.
// ---------------------------------------------------------------------------
__global__ void __launch_bounds__(256) finalize4(
        const int* __restrict__ gcnt, const int* __restrict__ pcnt,
        const float* __restrict__ partial, float* __restrict__ out) {
    int tid = threadIdx.x;
    __shared__ float sdsum[32];
    if (tid < 32) {
        float s = 0.0f;
        for (int k = 0; k < NCHD; ++k) s += partial[tid * NCHD + k];
        sdsum[tid] = s;
    }
    __syncthreads();
    if (tid == 0) {
        float sum = 0.0f;
        int nvalid = 0;
        for (int s = 0; s < NSLICE; ++s) {
            int ng = gcnt[s];
            int np_ = pcnt[s];
            if (ng > 0 && np_ > 0) {
                float ahd = 0.5f * (sdsum[s * 2 + 0] / (float)ng +
                                    sdsum[s * 2 + 1] / (float)np_);
                sum += 1.0f - 1.0f / (1.0f + ahd);
                nvalid++;
            }
        }
        out[0] = nvalid ? (sum / (float)nvalid) : NAN;
    }
}

// ---------------------------------------------------------------------------
// Workspace layout (bytes):
//   [0,       256K)    bm     : 2 x 16 x 256 x 4 u64  (mask bitmaps)
//   [262144,  512K)    ebm    : 2 x 16 x 256 x 4 u64  (truncated edge bitmaps)
//   [524288,  1M)      gpts   : 16 x 4096 float2
//   [1048576, 1.5M)    ppts   : 16 x 4096 float2
//   [1572864, +64)     gcnt   : 16 int
//   [1572928, +64)     pcnt   : 16 int
//   [1572992, +1K)     partial: 256 float
// ---------------------------------------------------------------------------
extern "C" void kernel_launch(void* const* d_in, const int* in_sizes, int n_in,
                              void* d_out, int out_size, void* d_ws, size_t ws_size,
                              hipStream_t stream) {
    const float* gth = (const float*)d_in[0];
    const float* pred = (const float*)d_in[1];
    float* out = (float*)d_out;
    char* ws = (char*)d_ws;

    u64* bm = (u64*)(ws);
    u64* ebm = (u64*)(ws + 262144);
    float2* gpts = (float2*)(ws + 524288);
    float2* ppts = (float2*)(ws + 1048576);
    int* gcnt = (int*)(ws + 1572864);
    int* pcnt = (int*)(ws + 1572928);
    float* partial = (float*)(ws + 1572992);

    binarize_pack<<<8192, 256, 0, stream>>>(gth, pred, bm);
    edge_compact<<<32, 256, 0, stream>>>(bm, gpts, ppts, ebm, gcnt, pcnt);
    edt_nn<<<32 * NCHD, 256, 139264, stream>>>(gpts, ppts, gcnt, pcnt,
                                               ebm, partial);
    finalize4<<<1, 256, 0, stream>>>(gcnt, pcnt, partial, out);
}

// Round 15
// 46.149 us; speedup vs baseline: 1.1604x; 1.1604x over previous
//
#include <hip/hip_runtime.h>
#include <math.h>

#define HH 256
#define WW 256
#define HWSZ (HH * WW)
#define KE 4096
#define NSLICE 16
#define NCH 64                 // query chunks of 64 per (slice,dir)
#define GSENT 1024             // empty-column sentinel: 1024^2 > max real d2 (130050)
#define RPB 32                 // rows per edt_vert block

typedef unsigned long long u64;
typedef unsigned short u16;

// ---------------------------------------------------------------------------
// K1: binarize + bit-pack (r6-verbatim). One block per image row (2 x 16 x
// 256 = 8192 blocks): full-chip BW for the only big read. Lane thresholds
// one pixel; ballot packs 64 cols -> u64 (exactly ONE load->ballot per
// thread, so no serialization). bm layout: [tensor][slice][row][word4].
// ---------------------------------------------------------------------------
__global__ void __launch_bounds__(256) binarize_pack(
        const float* __restrict__ gth, const float* __restrict__ pred,
        u64* __restrict__ bm) {
    int b = blockIdx.x;                 // tensor*4096 + slice*256 + row
    int tensor = b >> 12;
    int sr = b & 4095;
    const float* img = tensor ? pred : gth;
    float v = img[sr * WW + threadIdx.x];
    u64 bal = __ballot(v > 0.5f);
    if ((threadIdx.x & 63) == 0) bm[(size_t)b * 4 + (threadIdx.x >> 6)] = bal;
}

// ---------------------------------------------------------------------------
// K2: bitwise edge detect + ordered compaction + truncated edge bitmap.
// r6 logic; the only change is the prefix scan: wave-shfl scan + cross-wave
// combine (1 barrier) instead of Hillis-Steele (16 barriers). The wave-scan
// was validated absmax=0 in r8/r9/r10/r13.
// 32 blocks (tensor,slice), thread = row.
//   vert  = rowAbove & row & rowBelow      (OOB row = all-ones)
//   erode = vert & shl1 & shr1             (OOB col carry-in = 1)
//   edge  = row & ~erode
// Ordered point writes (row-major == jnp.nonzero); ebm keeps only bits of
// row-major rank < KE (reference sees only the first KE targets); cnt =
// FULL count (the divisor).
// ---------------------------------------------------------------------------
__global__ void __launch_bounds__(256) edge_compact(
        const u64* __restrict__ bm,
        float2* __restrict__ gpts, float2* __restrict__ ppts,
        u64* __restrict__ ebm,
        int* __restrict__ gcnt, int* __restrict__ pcnt) {
    int b = blockIdx.x;                 // 0..31  (tensor*16 + slice)
    int tensor = b >> 4;
    int slice = b & 15;
    const u64* rm = bm + (size_t)(tensor * 4096 + slice * 256) * 4;
    float2* pts = (tensor ? ppts : gpts) + slice * KE;
    int* cnt = (tensor ? pcnt : gcnt) + slice;
    u64* eb = ebm + (size_t)b * 1024;   // 256 rows x 4 words

    int row = threadIdx.x;
    u64 vc[4], va[4], vb[4];
#pragma unroll
    for (int w = 0; w < 4; ++w) {
        vc[w] = rm[row * 4 + w];
        va[w] = (row > 0) ? rm[(row - 1) * 4 + w] : ~0ull;
        vb[w] = (row < HH - 1) ? rm[(row + 1) * 4 + w] : ~0ull;
    }
    u64 vert[4];
#pragma unroll
    for (int w = 0; w < 4; ++w) vert[w] = va[w] & vc[w] & vb[w];
    u64 e[4];
#pragma unroll
    for (int w = 0; w < 4; ++w) {
        u64 left  = (vert[w] << 1) | ((w > 0) ? (vert[w - 1] >> 63) : 1ull);
        u64 right = (vert[w] >> 1) | (((w < 3) ? (vert[w + 1] & 1ull) : 1ull) << 63);
        e[w] = vc[w] & ~(vert[w] & left & right);
    }
    int mycnt = __popcll(e[0]) + __popcll(e[1]) + __popcll(e[2]) + __popcll(e[3]);

    // Wave-level inclusive scan + cross-wave combine (1 barrier).
    int lane = row & 63, wv = row >> 6;
    int incl = mycnt;
    for (int d = 1; d < 64; d <<= 1) {
        int n = __shfl_up(incl, d, 64);
        if (lane >= d) incl += n;
    }
    __shared__ int wsum[4];
    if (lane == 63) wsum[wv] = incl;
    __syncthreads();
    int wpre = 0;
    for (int k = 0; k < 4; ++k) wpre += (k < wv) ? wsum[k] : 0;
    int off = wpre + incl - mycnt;      // exclusive prefix (row-major rank)

    // Truncated edge bitmap: keep only bits with rank < KE.
    int rem = KE - off;
    u64 t[4];
    if (rem >= mycnt) {
#pragma unroll
        for (int w = 0; w < 4; ++w) t[w] = e[w];
    } else if (rem <= 0) {
#pragma unroll
        for (int w = 0; w < 4; ++w) t[w] = 0ull;
    } else {
        int k = rem;
#pragma unroll
        for (int w = 0; w < 4; ++w) {
            int pc = __popcll(e[w]);
            if (k >= pc) { t[w] = e[w]; k -= pc; }
            else {
                u64 bits = e[w], keep = 0ull;
                for (int i = 0; i < k; ++i) {
                    u64 low = bits & (~bits + 1ull);
                    keep |= low;
                    bits ^= low;
                }
                t[w] = keep;
                k = 0;
            }
        }
    }
#pragma unroll
    for (int w = 0; w < 4; ++w) eb[row * 4 + w] = t[w];

    // Ordered point-list writes (queries; first KE in row-major order).
    int o = off;
#pragma unroll
    for (int w = 0; w < 4; ++w) {
        u64 bits = e[w];
        while (bits) {
            int l = __ffsll((long long)bits) - 1;
            bits &= bits - 1;
            if (o < KE) pts[o] = make_float2((float)row, (float)(w * 64 + l));
            ++o;
        }
    }
    if (row == HH - 1) *cnt = wpre + incl;
}

// ---------------------------------------------------------------------------
// word_dist: distance from position p (may be <0 or >63) to the nearest set
// bit of w; GSENT if w empty. (r6-proven)
// ---------------------------------------------------------------------------
__device__ __forceinline__ int word_dist(u64 w, int p) {
    if (w == 0) return GSENT;
    int lo = __ffsll((long long)w) - 1;    // lowest set bit
    int hi = 63 - __clzll((long long)w);   // highest set bit
    if (p <= lo) return lo - p;
    if (p >= hi) return p - hi;
    u64 up = w >> p;                        // bits >= p (nonzero: hi > p)
    int du = __ffsll((long long)up) - 1;
    u64 dn = w << (63 - p);                 // bits <= p (nonzero: lo < p)
    int dd = __clzll((long long)dn);
    return min(du, dd);
}

// ---------------------------------------------------------------------------
// K3: vertical EDT, fully parallel (r6-verbatim). 32 maps x 8 row-blocks =
// 256 blocks x 256 threads (shape matters: 8 CUs/map keeps per-CU work ~4k
// cycles; the 1-block/CU fused variants were 8x slower). Stage the 8 KB edge
// bitmap in LDS (broadcast reads). Thread = column: gather the column's 256
// bits into 4 registers, then for each of the block's 32 rows compute
// G[r][c] = min over 4 words of word_dist. Coalesced u16 stores (L2-hot).
// ---------------------------------------------------------------------------
__global__ void __launch_bounds__(256) edt_vert(
        const u64* __restrict__ ebm, u16* __restrict__ G16) {
    int map = blockIdx.x >> 3;
    int rblk = blockIdx.x & 7;
    const u64* eb = ebm + (size_t)map * 1024;
    u16* G = G16 + (size_t)map * HWSZ;

    __shared__ u64 ebl[1024];
    int tid = threadIdx.x;
    for (int i = tid; i < 1024; i += 256) ebl[i] = eb[i];
    __syncthreads();

    int c = tid, cw = c >> 6, cb = c & 63;
    u64 w0 = 0, w1 = 0, w2 = 0, w3 = 0;
#pragma unroll 4
    for (int r = 0; r < 64; ++r) {
        w0 |= ((ebl[(r      ) * 4 + cw] >> cb) & 1ull) << r;
        w1 |= ((ebl[(r +  64) * 4 + cw] >> cb) & 1ull) << r;
        w2 |= ((ebl[(r + 128) * 4 + cw] >> cb) & 1ull) << r;
        w3 |= ((ebl[(r + 192) * 4 + cw] >> cb) & 1ull) << r;
    }

    int r0 = rblk * RPB;
#pragma unroll 4
    for (int i = 0; i < RPB; ++i) {
        int r = r0 + i;
        int d = word_dist(w0, r);
        d = min(d, word_dist(w1, r - 64));
        d = min(d, word_dist(w2, r - 128));
        d = min(d, word_dist(w3, r - 192));
        G[r * WW + c] = (u16)min(d, GSENT);
    }
}

// ---------------------------------------------------------------------------
// K4: per-query NN distance via column scan of the vertical EDT (r6-verbatim).
// Grid = 32 (slice,dir) x 64 chunks of 64 queries = 2048 blocks x 64 thr.
// d2(q) = min_{c'} ((c-c')^2 + G[r][c']^2) -- exact integers, fixed 256
// candidates, 32 independent int4 loads -> deep MLP, no divergence.
// Plain partial store, no atomics (atomic tails measured -11..-70 us).
// ---------------------------------------------------------------------------
__global__ void __launch_bounds__(64) nn_gather(
        const float2* __restrict__ gpts, const float2* __restrict__ ppts,
        const int* __restrict__ gcnt, const int* __restrict__ pcnt,
        const u16* __restrict__ G16, float* __restrict__ partial) {
    int b = blockIdx.x;                 // sd*NCH + chunk
    int chunk = b & (NCH - 1);
    int sd = b >> 6;                    // slice*2 + dir
    int dir = sd & 1;
    int slice = sd >> 1;
    int tid = threadIdx.x;

    int qfull = dir ? pcnt[slice] : gcnt[slice];
    int qc = min(qfull, KE);
    int qi = chunk * 64 + tid;

    float val = 0.0f;
    if (qi < qc) {
        const float2* q = (dir ? ppts : gpts) + slice * KE;
        int tt = dir ? 0 : 1;           // target map tensor
        const u16* G = G16 + (size_t)(tt * 16 + slice) * HWSZ;
        float2 qp = q[qi];
        int r = (int)qp.x, c = (int)qp.y;
        const int4* grow = (const int4*)(G + r * WW);   // 256 u16 = 32 int4
        int m = 0x7fffffff;
#pragma unroll
        for (int j = 0; j < 32; ++j) {
            int4 v = grow[j];
            int base = j * 8;
#define STEP(word, k0)                                                      \
            {                                                               \
                int g0 = (word) & 0xffff;                                   \
                int g1 = (int)(((unsigned)(word)) >> 16);                   \
                int dc0 = c - (base + k0);                                  \
                int dc1 = c - (base + k0 + 1);                              \
                m = min(m, dc0 * dc0 + g0 * g0);                            \
                m = min(m, dc1 * dc1 + g1 * g1);                            \
            }
            STEP(v.x, 0) STEP(v.y, 2) STEP(v.z, 4) STEP(v.w, 6)
#undef STEP
        }
        val = sqrtf((float)m);
    }
    for (int s = 32; s > 0; s >>= 1) val += __shfl_xor(val, s, 64);
    if (tid == 0) partial[b] = val;
}

// ---------------------------------------------------------------------------
// K5: fold 2048 partials -> per-slice ahd -> loss -> nanmean (r6-verbatim).
// 1 block x 512 threads.
// ---------------------------------------------------------------------------
__global__ void __launch_bounds__(512) finalize3(
        const int* __restrict__ gcnt, const int* __restrict__ pcnt,
        const float* __restrict__ partial, float* __restrict__ out) {
    int tid = threadIdx.x;
    float v = partial[tid * 4] + partial[tid * 4 + 1] +
              partial[tid * 4 + 2] + partial[tid * 4 + 3];
    v += __shfl_xor(v, 1, 16);
    v += __shfl_xor(v, 2, 16);
    v += __shfl_xor(v, 4, 16);
    v += __shfl_xor(v, 8, 16);
    __shared__ float sdsum[32];
    if ((tid & 15) == 0) sdsum[tid >> 4] = v;
    __syncthreads();
    if (tid == 0) {
        float sum = 0.0f;
        int nvalid = 0;
        for (int s = 0; s < NSLICE; ++s) {
            int ng = gcnt[s];
            int np_ = pcnt[s];
            if (ng > 0 && np_ > 0) {
                float ahd = 0.5f * (sdsum[s * 2 + 0] / (float)ng +
                                    sdsum[s * 2 + 1] / (float)np_);
                sum += 1.0f - 1.0f / (1.0f + ahd);
                nvalid++;
            }
        }
        out[0] = nvalid ? (sum / (float)nvalid) : NAN;
    }
}

// ---------------------------------------------------------------------------
// Workspace layout (bytes):
//   [0,       256K)    bm     : 2 x 16 x 256 x 4 u64  (mask bitmaps)
//   [262144,  512K)    ebm    : 2 x 16 x 256 x 4 u64  (truncated edge bitmaps)
//   [524288,  1M)      gpts   : 16 x 4096 float2
//   [1048576, 1.5M)    ppts   : 16 x 4096 float2
//   [1572864, 5767168) G16    : 32 maps x 256 x 256 u16 (vertical EDT)
//   [5767168, +64)     gcnt   : 16 int
//   [5767232, +64)     pcnt   : 16 int
//   [5767296, +8K)     partial: 2048 float
// ---------------------------------------------------------------------------
extern "C" void kernel_launch(void* const* d_in, const int* in_sizes, int n_in,
                              void* d_out, int out_size, void* d_ws, size_t ws_size,
                              hipStream_t stream) {
    const float* gth = (const float*)d_in[0];
    const float* pred = (const float*)d_in[1];
    float* out = (float*)d_out;
    char* ws = (char*)d_ws;

    u64* bm = (u64*)(ws);
    u64* ebm = (u64*)(ws + 262144);
    float2* gpts = (float2*)(ws + 524288);
    float2* ppts = (float2*)(ws + 1048576);
    u16* G16 = (u16*)(ws + 1572864);
    int* gcnt = (int*)(ws + 5767168);
    int* pcnt = (int*)(ws + 5767232);
    float* partial = (float*)(ws + 5767296);

    binarize_pack<<<8192, 256, 0, stream>>>(gth, pred, bm);
    edge_compact<<<32, 256, 0, stream>>>(bm, gpts, ppts, ebm, gcnt, pcnt);
    edt_vert<<<256, 256, 0, stream>>>(ebm, G16);
    nn_gather<<<NSLICE * 2 * NCH, 64, 0, stream>>>(gpts, ppts, gcnt, pcnt,
                                                   G16, partial);
    finalize3<<<1, 512, 0, stream>>>(gcnt, pcnt, partial, out);
}